// Round 15
// baseline (420.765 us; speedup 1.0000x reference)
//
#include <hip/hip_runtime.h>
#include <hip/hip_bf16.h>
#include <math.h>

// ---------------------------------------------------------------------------
// DeepDCNN: emb-gather -> 4x [grouped full-conv + pair-fold + ordered top-k +
// tanh] -> FC.  All fp32.
// K1 = L1+L2 fused through LDS (Z1 never hits HBM).  L3, L4 separate
// (measured: fusing them serialized 1 block/CU and lost ~25us).
// Convs use packed-fp32 FMA (v_pk_fma_f32): the two filters each wave owns
// are the vector halves — perfect alignment, window splat via op_sel.
// Top-k = wave-level radix select (ballot + s_bcnt): 8-ary for L1 chains
// (serial-step bound: binary->4-ary was 126->105us), binary for conv chains
// (4-ary measured -25us there).
// ---------------------------------------------------------------------------

typedef float v2f __attribute__((ext_vector_type(2)));

#if defined(__has_builtin)
#if __has_builtin(__builtin_amdgcn_ballot_w64)
#define BALLOT64(expr) __builtin_amdgcn_ballot_w64(expr)
#endif
#endif
#ifndef BALLOT64
#define BALLOT64(expr) __ballot(expr)
#endif

__device__ __forceinline__ unsigned f2ord(float f) {
    unsigned u = __float_as_uint(f);
    return (u & 0x80000000u) ? ~u : (u | 0x80000000u);
}
__device__ __forceinline__ float ord2f(unsigned key) {
    unsigned u = (key & 0x80000000u) ? (key & 0x7fffffffu) : ~key;
    return __uint_as_float(u);
}
// tanh via exp + hw rcp: 1 - 2*rcp(e^{2x}+1).  |err| ~1e-7.  Keys are
// pre-tanh so selection ordering is unaffected.
__device__ __forceinline__ float tanh_fast(float x) {
    float e = __expf(2.f * x);
    return 1.f - 2.f * __builtin_amdgcn_rcpf(e + 1.f);
}
__device__ __forceinline__ int mbcnt64(unsigned long long m) {
    return __builtin_amdgcn_mbcnt_hi((unsigned)(m >> 32),
           __builtin_amdgcn_mbcnt_lo((unsigned)m, 0u));
}

// wave-total count of keys >= t  (1 v_cmp -> SGPR pair; s_bcnt pipelines
// under the next v_cmp burst)
template<int CH>
__device__ __forceinline__ int count_ge(const unsigned* keys, unsigned t) {
    int c = 0;
    #pragma unroll
    for (int i = 0; i < CH; ++i)
        c += __popcll(BALLOT64((keys[i] >= t)));
    return c;
}

// ---- compaction + tanh scatter into stage; optional coalesced copy-out ---
// T = threshold key (low bits may be zeroed by early exit; then ALL bucket
// members are kept).  Stable (earliest ties), order-preserving.
// If out == nullptr, stage IS the final destination (LDS row) — no copy.
template<int CH>
__device__ __forceinline__ void select_finish(const unsigned* keys, unsigned T,
                                              int k, float* stage,
                                              float* __restrict__ out)
{
    int g = 0, e = 0;
    #pragma unroll
    for (int i = 0; i < CH; ++i) { g += (keys[i] > T); e += (keys[i] == T); }

    int gtBefore = 0, eqBefore = 0, totG = 0;
    #pragma unroll
    for (int b = 0; b < 5; ++b) {     // CH <= 17 < 32 -> 5 bits
        unsigned long long mg = BALLOT64((((g >> b) & 1) != 0));
        unsigned long long me = BALLOT64((((e >> b) & 1) != 0));
        gtBefore += mbcnt64(mg) << b;
        eqBefore += mbcnt64(me) << b;
        totG     += __popcll(mg) << b;
    }
    const int needTies = k - totG;    // # of ==T to keep (earliest)

    int gRun = 0, eRun = 0;
    #pragma unroll
    for (int i = 0; i < CH; ++i) {
        const unsigned key = keys[i];
        const bool isG = key > T;
        const bool isE = key == T;
        const int eIdx = eqBefore + eRun;
        const int dst = gtBefore + gRun + min(eIdx, needTies);
        if (isG || (isE && eIdx < needTies))
            stage[dst] = tanh_fast(ord2f(key));
        gRun += isG; eRun += isE;
    }
    if (out) {  // coalesced float4 copy-out (k % 4 == 0, 16B-aligned)
        const int lane = threadIdx.x & 63;
        float4* o4 = (float4*)out;
        const float4* s4 = (const float4*)stage;
        for (int i = lane; i < (k >> 2); i += 64)
            o4[i] = s4[i];
    }
}

// ---- N-row exact top-k, RADIX-ary interleaved chains w/ early exit -------
// Lane holds contiguous chunk [lane*CH, ...) of each row as order-keys in
// regs; invalid slots MUST be 0 (k < real element count everywhere, so
// padding can never enter the kept set).
template<int N, int CH, int RADIX>
__device__ void wave_selectN(const unsigned (*keys)[CH], int k,
                             float* const* stages, float* const* outs)
{
    unsigned p[N];
    int above[N], buck[N];
    #pragma unroll
    for (int n = 0; n < N; ++n) { p[n] = 0u; above[n] = 0; buck[n] = 64 * CH; }

    unsigned doneMask = 0;
    const unsigned allDone = (1u << N) - 1u;

    if (RADIX == 8) {
        // step 0: top 2 bits (4-ary; q<<30, q<=3 avoids u32 overflow)
        #pragma unroll
        for (int n = 0; n < N; ++n) {
            const int c1 = count_ge<CH>(keys[n], 1u << 30);
            const int c2 = count_ge<CH>(keys[n], 2u << 30);
            const int c3 = count_ge<CH>(keys[n], 3u << 30);
            const int rem = k;
            if (c3 >= rem)      { p[n] = 3u << 30; buck[n] = c3; }
            else if (c2 >= rem) { p[n] = 2u << 30; buck[n] = c2 - c3; above[n] = c3; }
            else if (c1 >= rem) { p[n] = 1u << 30; buck[n] = c1 - c2; above[n] = c2; }
            else                { buck[n] -= c1; above[n] = c1; }
            if (buck[n] == k - above[n]) doneMask |= (1u << n);
        }
        // steps 1..10: 3 bits each
        #pragma unroll 1
        for (int pos = 9; pos >= 0; --pos) {
            #pragma unroll
            for (int n = 0; n < N; ++n) {
                if (!((doneMask >> n) & 1u)) {    // wave-uniform branch
                    const int sh = 3 * pos;
                    const int c1 = count_ge<CH>(keys[n], p[n] | (1u << sh));
                    const int c2 = count_ge<CH>(keys[n], p[n] | (2u << sh));
                    const int c3 = count_ge<CH>(keys[n], p[n] | (3u << sh));
                    const int c4 = count_ge<CH>(keys[n], p[n] | (4u << sh));
                    const int c5 = count_ge<CH>(keys[n], p[n] | (5u << sh));
                    const int c6 = count_ge<CH>(keys[n], p[n] | (6u << sh));
                    const int c7 = count_ge<CH>(keys[n], p[n] | (7u << sh));
                    const int ab = above[n];
                    const int rem = k - ab;
                    if      (c7 - ab >= rem) { p[n] |= 7u << sh; buck[n] = c7 - ab; }
                    else if (c6 - ab >= rem) { p[n] |= 6u << sh; buck[n] = c6 - c7; above[n] = c7; }
                    else if (c5 - ab >= rem) { p[n] |= 5u << sh; buck[n] = c5 - c6; above[n] = c6; }
                    else if (c4 - ab >= rem) { p[n] |= 4u << sh; buck[n] = c4 - c5; above[n] = c5; }
                    else if (c3 - ab >= rem) { p[n] |= 3u << sh; buck[n] = c3 - c4; above[n] = c4; }
                    else if (c2 - ab >= rem) { p[n] |= 2u << sh; buck[n] = c2 - c3; above[n] = c3; }
                    else if (c1 - ab >= rem) { p[n] |= 1u << sh; buck[n] = c1 - c2; above[n] = c2; }
                    else                     { buck[n] -= (c1 - ab); above[n] = c1; }
                    if (buck[n] == k - above[n]) doneMask |= (1u << n);
                }
            }
            if (doneMask == allDone) break;
        }
    } else {
        #pragma unroll 1
        for (int pos = 31; pos >= 0; --pos) {
            #pragma unroll
            for (int n = 0; n < N; ++n) {
                if (!((doneMask >> n) & 1u)) {    // wave-uniform branch
                    const unsigned t = p[n] | (1u << pos);
                    const int c = count_ge<CH>(keys[n], t);
                    const int inb = c - above[n];
                    const int rem = k - above[n];
                    if (inb >= rem) { p[n] = t; buck[n] = inb; }
                    else            { above[n] += inb; buck[n] -= inb; }
                    if (buck[n] == k - above[n]) doneMask |= (1u << n);
                }
            }
            if (doneMask == allDone) break;
        }
    }
    #pragma unroll
    for (int n = 0; n < N; ++n)
        select_finish<CH>(keys[n], p[n], k, stages[n], outs[n]);
}

// ---------------------------------------------------------------------------
// K1: L1 + L2 fused.  grid (16 j2, 64 b), block 640 = 10 waves.
//  L1: wave w -> group jj=w/5, filters q=w%5 and q+5 (dual 8-ary chains,
//      packed keygen); selects scatter into padded LDS rows z1[20][840].
//  L2: waves 0..6, filters 2w/2w+1 (packed conv, dual binary chains) -> Z2.
// ---------------------------------------------------------------------------
#define L1RW 1100   // padded gather row width
#define Z1W  840    // 4 zero-pad + 768 data + zero tail (>= 64*13+4 = 836)

__global__ __launch_bounds__(640) void l12_fused(
    const int* __restrict__ tokens, const float* __restrict__ emb,
    const float* __restrict__ W1, const float* __restrict__ B1,
    const float* __restrict__ W2, const float* __restrict__ B2,
    float* __restrict__ Z2)
{
    const int j2 = blockIdx.x;   // 0..15
    const int b  = blockIdx.y;   // 0..63
    const int t  = threadIdx.x;
    const int wav  = __builtin_amdgcn_readfirstlane(t >> 6);  // 0..9
    const int lane = t & 63;

    __shared__ __align__(16) float xr[4][L1RW];   // 17.6 KB (reused as L2 stage)
    __shared__ __align__(16) float z1[20][Z1W];   // 67.2 KB

    const float4* emb4 = (const float4*)emb;   // E=64 floats = 16 float4
    for (int i = t; i < L1RW; i += 640) {
        int s = i - 6;
        float4 v = make_float4(0.f, 0.f, 0.f, 0.f);
        if (s >= 0 && s < 1024) {
            int tok = tokens[b * 1024 + s];
            v = emb4[(size_t)tok * 16 + j2];
        }
        xr[0][i] = v.x; xr[1][i] = v.y; xr[2][i] = v.z; xr[3][i] = v.w;
    }
    {   // zero z1 pad columns [0,4) and [772,Z1W)
        const int PERROW = 4 + (Z1W - 772);
        for (int i = t; i < 20 * PERROW; i += 640) {
            int r = i / PERROW, p = i - r * PERROW;
            z1[r][(p < 4) ? p : (772 + p - 4)] = 0.f;
        }
    }
    __syncthreads();

    // ---- L1 (packed keygen: vector halves = the wave's 2 filters) ----
    {
        const int jj = wav / 5;
        const int q  = wav % 5;
        const int jg = 2 * j2 + jj;
        const int beg = lane * 17;

        float x0[23], x1[23];
        #pragma unroll
        for (int i = 0; i < 23; ++i) {
            x0[i] = xr[2 * jj][beg + i];
            x1[i] = xr[2 * jj + 1][beg + i];
        }

        v2f vwa[7], vwb[7];
        #pragma unroll
        for (int k2 = 0; k2 < 7; ++k2) {
            v2f a = { W1[(2 * jg * 10 + q) * 7 + k2],
                      W1[(2 * jg * 10 + q + 5) * 7 + k2] };
            v2f bb = { W1[((2 * jg + 1) * 10 + q) * 7 + k2],
                       W1[((2 * jg + 1) * 10 + q + 5) * 7 + k2] };
            vwa[k2] = a; vwb[k2] = bb;
        }
        v2f vbias = { B1[2 * jg * 10 + q]     + B1[(2 * jg + 1) * 10 + q],
                      B1[2 * jg * 10 + q + 5] + B1[(2 * jg + 1) * 10 + q + 5] };

        unsigned keys[2][17];
        #pragma unroll
        for (int i = 0; i < 17; ++i) {
            v2f acc = vbias;
            #pragma unroll
            for (int k2 = 0; k2 < 7; ++k2) {
                v2f s0 = { x0[i + k2], x0[i + k2] };
                v2f s1 = { x1[i + k2], x1[i + k2] };
                acc = __builtin_elementwise_fma(s0, vwa[k2], acc);
                acc = __builtin_elementwise_fma(s1, vwb[k2], acc);
            }
            const bool ok = (beg + i < 1030);
            keys[0][i] = ok ? f2ord(acc.x) : 0u;
            keys[1][i] = ok ? f2ord(acc.y) : 0u;
        }
        float* stages[2] = { &z1[jj * 10 + q][4], &z1[jj * 10 + q + 5][4] };
        float* outs[2] = { nullptr, nullptr };
        wave_selectN<2, 17, 8>(keys, 768, stages, outs);
    }
    __syncthreads();

    // ---- L2 (packed conv; dual binary chains) ----
    if (wav < 7) {
        const int f0 = 2 * wav;
        const int base = lane * 13;
        v2f vacc[13];
        {
            v2f vb = { B2[2 * j2 * 14 + f0]     + B2[(2 * j2 + 1) * 14 + f0],
                       B2[2 * j2 * 14 + f0 + 1] + B2[(2 * j2 + 1) * 14 + f0 + 1] };
            #pragma unroll
            for (int i = 0; i < 13; ++i) vacc[i] = vb;
        }
        #pragma unroll 1
        for (int r = 0; r < 20; ++r) {
            const int h = r / 10, c = r - 10 * (r / 10);
            float win[17];
            #pragma unroll
            for (int p = 0; p < 17; ++p) win[p] = z1[r][base + p];
            const float* Wp = W2 + ((size_t)((2 * j2 + h) * 14 + f0) * 10 + c) * 5;
            #pragma unroll
            for (int k2 = 0; k2 < 5; ++k2) {
                v2f vw = { Wp[k2], Wp[50 + k2] };   // filters f0, f0+1
                #pragma unroll
                for (int i = 0; i < 13; ++i) {
                    v2f s = { win[i + k2], win[i + k2] };
                    vacc[i] = __builtin_elementwise_fma(s, vw, vacc[i]);
                }
            }
        }
        unsigned keys[2][13];
        #pragma unroll
        for (int i = 0; i < 13; ++i) {
            const bool ok = (base + i < 772);
            keys[0][i] = ok ? f2ord(vacc[i].x) : 0u;
            keys[1][i] = ok ? f2ord(vacc[i].y) : 0u;
        }
        float* st = &xr[0][0] + wav * 512;     // xr dead after L1 -> reuse
        float* stages[2] = { st, st };
        const size_t orow = (size_t)b * 224 + (size_t)j2 * 14;
        float* outs[2] = { Z2 + (orow + f0) * 512, Z2 + (orow + f0 + 1) * 512 };
        wave_selectN<2, 13, 2>(keys, 512, stages, outs);
    }
}

// ---------------------------------------------------------------------------
// Conv + fold + select + tanh (L3, L4).  grid (G/2 j, 64 b), block NW*64.
// Wave w: filters 2w, 2w+1 (packed conv, dual binary chains) -> Z (global).
// ---------------------------------------------------------------------------
template <int IPG, int NF, int K, int SIN, int SOUT, int KSEL, int NW, int CH>
__global__ __launch_bounds__(NW * 64) void conv_fold_select_kernel(
    const float* __restrict__ X, const float* __restrict__ W,
    const float* __restrict__ Bias, float* __restrict__ Z,
    int Cin, int Cfold)
{
    static_assert(NF == 2 * NW, "2 filters per wave");
    static_assert(64 * CH >= SOUT, "chunk covers row");
    constexpr int W2 = 64 * CH + K - 1;

    const int t = threadIdx.x;
    const int j = blockIdx.x;
    const int b = blockIdx.y;
    const int wav = __builtin_amdgcn_readfirstlane(t >> 6);
    const int lane = t & 63;

    __shared__ float xs[2 * IPG][W2];
    __shared__ __align__(16) float stagebuf[NW][KSEL];

    const float* Xb = X + ((size_t)b * Cin + (size_t)(2 * j) * IPG) * SIN;
    for (int idx = t; idx < 2 * IPG * W2; idx += NW * 64) {
        int r = idx / W2, p = idx - r * W2;
        int sg = p - (K - 1);
        xs[r][p] = (sg >= 0 && sg < SIN) ? Xb[(size_t)r * SIN + sg] : 0.f;
    }
    __syncthreads();

    const int f0 = 2 * wav;
    v2f vacc[CH];
    {
        v2f vb = { Bias[2 * j * NF + f0]     + Bias[(2 * j + 1) * NF + f0],
                   Bias[2 * j * NF + f0 + 1] + Bias[(2 * j + 1) * NF + f0 + 1] };
        #pragma unroll
        for (int i = 0; i < CH; ++i) vacc[i] = vb;
    }
    const int base = lane * CH;

    #pragma unroll 1
    for (int r = 0; r < 2 * IPG; ++r) {
        const int h = r / IPG, c = r - IPG * (r / IPG);
        float win[CH + K - 1];
        #pragma unroll
        for (int p = 0; p < CH + K - 1; ++p)
            win[p] = xs[r][base + p];
        const float* Wp = W + ((size_t)((2 * j + h) * NF + f0) * IPG + c) * K;
        #pragma unroll
        for (int k2 = 0; k2 < K; ++k2) {
            v2f vw = { Wp[k2], Wp[(size_t)IPG * K + k2] };
            #pragma unroll
            for (int i = 0; i < CH; ++i) {
                v2f s = { win[i + k2], win[i + k2] };
                vacc[i] = __builtin_elementwise_fma(s, vw, vacc[i]);
            }
        }
    }

    unsigned keys[2][CH];
    #pragma unroll
    for (int i = 0; i < CH; ++i) {
        const bool ok = (base + i < SOUT);
        keys[0][i] = ok ? f2ord(vacc[i].x) : 0u;
        keys[1][i] = ok ? f2ord(vacc[i].y) : 0u;
    }
    const size_t orow = (size_t)b * Cfold + (size_t)j * NF;
    float* stages[2] = { stagebuf[wav], stagebuf[wav] };
    float* outs[2] = { Z + (orow + f0) * (size_t)KSEL,
                       Z + (orow + f0 + 1) * (size_t)KSEL };
    wave_selectN<2, CH, 2>(keys, KSEL, stages, outs);
}

// ---------------------------------------------------------------------------
// FC: (64,352) @ (6,352)^T + b
// ---------------------------------------------------------------------------
__global__ __launch_bounds__(192) void fc_kernel(
    const float* __restrict__ Z, const float* __restrict__ Wf,
    const float* __restrict__ bf, float* __restrict__ out)
{
    int g = blockIdx.x * blockDim.x + threadIdx.x;
    if (g >= 64 * 6) return;
    int b = g / 6, c = g % 6;
    float acc = bf[c];
    const float* zr = Z + b * 352;
    const float* wr = Wf + c * 352;
    for (int i = 0; i < 352; ++i) acc += zr[i] * wr[i];
    out[g] = acc;
}

extern "C" void kernel_launch(void* const* d_in, const int* in_sizes, int n_in,
                              void* d_out, int out_size, void* d_ws, size_t ws_size,
                              hipStream_t stream)
{
    const int*   tokens = (const int*)  d_in[0];
    const float* emb    = (const float*)d_in[1];
    const float* w1     = (const float*)d_in[2];
    const float* b1     = (const float*)d_in[3];
    const float* w2     = (const float*)d_in[4];
    const float* b2     = (const float*)d_in[5];
    const float* w3     = (const float*)d_in[6];
    const float* b3     = (const float*)d_in[7];
    const float* w4     = (const float*)d_in[8];
    const float* b4     = (const float*)d_in[9];
    const float* fcw    = (const float*)d_in[10];
    const float* fcb    = (const float*)d_in[11];
    float* out = (float*)d_out;
    float* ws  = (float*)d_ws;

    // workspace (floats):
    //  Z2 [0,       7340032)   64*224*512  (29 MB)
    //  Z3 [7340032, 9699328)   64*144*256
    //  Z4 [9699328, 9721856)   64*88*4
    float* Z2 = ws;
    float* Z3 = ws + 7340032;
    float* Z4 = ws + 9699328;

    l12_fused<<<dim3(16, 64), 640, 0, stream>>>(tokens, emb, w1, b1, w2, b2, Z2);

    // L3: IPG=14 NF=18 K=5  512->516, keep 256.  NW=9, CH=9
    conv_fold_select_kernel<14, 18, 5, 512, 516, 256, 9, 9>
        <<<dim3(8, 64), 9 * 64, 0, stream>>>(Z2, w3, b3, Z3, 224, 144);

    // L4: IPG=18 NF=22 K=3  256->258, keep 4.    NW=11, CH=5
    conv_fold_select_kernel<18, 22, 3, 256, 258, 4, 11, 5>
        <<<dim3(4, 64), 11 * 64, 0, stream>>>(Z3, w4, b4, Z4, 144, 88);

    fc_kernel<<<2, 192, 0, stream>>>(Z4, fcw, fcb, out);
}